// Round 1
// baseline (567.520 us; speedup 1.0000x reference)
//
#include <hip/hip_runtime.h>

#define SEQ 4096
#define DK  128
#define ROW (SEQ * DK)          // elements per (s,d) plane = 524288
#define ROW4 (ROW / 4)          // float4 elements per plane = 131072

// Native vector type so __builtin_nontemporal_load/store accept it directly.
typedef float f4 __attribute__((ext_vector_type(4)));

// ---------------------------------------------------------------------------
// Kernel A: extract diagonal of R into diagT[s*DK + d] = R[(d*DK+d)*SEQ + s].
// 2 MiB output; coalesced writes. Runs in a few microseconds.
// ---------------------------------------------------------------------------
__global__ void extract_diag_kernel(const float* __restrict__ R,
                                    float* __restrict__ diagT) {
    int idx = blockIdx.x * blockDim.x + threadIdx.x;   // 0 .. ROW-1
    if (idx < ROW) {
        int d = idx & (DK - 1);
        int s = idx >> 7;                              // idx / DK
        diagT[idx] = R[(size_t)(d * DK + d) * SEQ + s];
    }
}

// ---------------------------------------------------------------------------
// Kernel B: out4[i] = x4[i] * diagT4[i mod ROW4].
//  - grid-stride, 2048 blocks x 256 thr (8 blocks/CU, 32 waves/CU), unroll x4
//    with stride-spaced indices -> 4 independent load pairs in flight/thread.
//  - x is read once and out written once: nontemporal (nt) so the 512 MiB
//    stream does not evict the 2 MiB L2-resident diagT (cached-path loads).
// ---------------------------------------------------------------------------
__global__ __launch_bounds__(256) void rope_scale_kernel(
        const f4* __restrict__ x,
        const f4* __restrict__ diagT,
        f4* __restrict__ out, int n4) {
    const int stride = gridDim.x * blockDim.x;
    int i = blockIdx.x * blockDim.x + threadIdx.x;

    for (; i + 3 * stride < n4; i += 4 * stride) {
        int i0 = i, i1 = i + stride, i2 = i + 2 * stride, i3 = i + 3 * stride;
        f4 x0 = __builtin_nontemporal_load(&x[i0]);
        f4 x1 = __builtin_nontemporal_load(&x[i1]);
        f4 x2 = __builtin_nontemporal_load(&x[i2]);
        f4 x3 = __builtin_nontemporal_load(&x[i3]);
        f4 d0 = diagT[i0 & (ROW4 - 1)];
        f4 d1 = diagT[i1 & (ROW4 - 1)];
        f4 d2 = diagT[i2 & (ROW4 - 1)];
        f4 d3 = diagT[i3 & (ROW4 - 1)];
        __builtin_nontemporal_store(x0 * d0, &out[i0]);
        __builtin_nontemporal_store(x1 * d1, &out[i1]);
        __builtin_nontemporal_store(x2 * d2, &out[i2]);
        __builtin_nontemporal_store(x3 * d3, &out[i3]);
    }
    for (; i < n4; i += stride) {
        f4 xv = __builtin_nontemporal_load(&x[i]);
        f4 dv = diagT[i & (ROW4 - 1)];
        __builtin_nontemporal_store(xv * dv, &out[i]);
    }
}

// ---------------------------------------------------------------------------
// Fallback (ws too small): fused kernel reading R's diagonal directly; the
// touched diagonal lines are L2-resident after the first (b,h) plane.
// ---------------------------------------------------------------------------
__global__ void rope_scale_fused_kernel(const f4* __restrict__ x,
                                        const float* __restrict__ R,
                                        f4* __restrict__ out, int n4) {
    const int stride = gridDim.x * blockDim.x;
    for (int i = blockIdx.x * blockDim.x + threadIdx.x; i < n4; i += stride) {
        int r  = i & (ROW4 - 1);     // float4 index within one (s,d) plane
        int s  = r >> 5;             // DK/4 = 32 float4 per row
        int d0 = (r & 31) * 4;       // first of 4 consecutive d
        f4 xv = __builtin_nontemporal_load(&x[i]);
        f4 dv;
        dv.x = R[(size_t)((d0 + 0) * DK + (d0 + 0)) * SEQ + s];
        dv.y = R[(size_t)((d0 + 1) * DK + (d0 + 1)) * SEQ + s];
        dv.z = R[(size_t)((d0 + 2) * DK + (d0 + 2)) * SEQ + s];
        dv.w = R[(size_t)((d0 + 3) * DK + (d0 + 3)) * SEQ + s];
        __builtin_nontemporal_store(xv * dv, &out[i]);
    }
}

extern "C" void kernel_launch(void* const* d_in, const int* in_sizes, int n_in,
                              void* d_out, int out_size, void* d_ws, size_t ws_size,
                              hipStream_t stream) {
    const float* x = (const float*)d_in[0];
    // d_in[1] = token_positions — unused by the reference.
    const float* R = (const float*)d_in[2];
    float* out = (float*)d_out;

    const int n  = out_size;        // 8*16*4096*128 = 67,108,864 elements
    const int n4 = n / 4;           // 16,777,216 float4 elements

    const size_t diag_bytes = (size_t)ROW * sizeof(float);   // 2 MiB
    const int GRID = 2048;          // 8 blocks/CU on 256 CUs, grid-stride

    if (ws_size >= diag_bytes) {
        float* diagT = (float*)d_ws;
        extract_diag_kernel<<<(ROW + 255) / 256, 256, 0, stream>>>(R, diagT);
        rope_scale_kernel<<<GRID, 256, 0, stream>>>(
            (const f4*)x, (const f4*)diagT, (f4*)out, n4);
    } else {
        rope_scale_fused_kernel<<<GRID, 256, 0, stream>>>(
            (const f4*)x, R, (f4*)out, n4);
    }
}

// Round 2
// 545.187 us; speedup vs baseline: 1.0410x; 1.0410x over previous
//
#include <hip/hip_runtime.h>

#define SEQ 4096
#define DK  128
#define ROW (SEQ * DK)          // elements per (s,d) plane = 524288
#define ROW4 (ROW / 4)          // float4 elements per plane = 131072

typedef float f4 __attribute__((ext_vector_type(4)));

// ---------------------------------------------------------------------------
// Kernel A: extract diagonal of R into diagT[s*DK + d] = R[(d*DK+d)*SEQ + s].
// 2 MiB output; coalesced writes. Runs in a few microseconds.
// ---------------------------------------------------------------------------
__global__ void extract_diag_kernel(const float* __restrict__ R,
                                    float* __restrict__ diagT) {
    int idx = blockIdx.x * blockDim.x + threadIdx.x;   // 0 .. ROW-1
    if (idx < ROW) {
        int d = idx & (DK - 1);
        int s = idx >> 7;                              // idx / DK
        diagT[idx] = R[(size_t)(d * DK + d) * SEQ + s];
    }
}

// ---------------------------------------------------------------------------
// Kernel B: out4[i] = x4[i] * diagT4[i mod ROW4].
// One-shot indexing (no grid-stride), 4 float4 per thread in consecutive
// 256-float4 segments: block covers 1024 contiguous float4 (16 KiB), every
// load/store instruction fully coalesced (4 KiB/wave-instr).  4 independent
// load pairs in flight per thread -> 4x bytes-in-flight vs round 0.
// Plain loads/stores (nt hints measured -27us in round 1).
// diagT stays L2-resident: per XCD the touched slice is a fixed 256 KiB.
// ---------------------------------------------------------------------------
__global__ __launch_bounds__(256) void rope_scale_kernel(
        const f4* __restrict__ x,
        const f4* __restrict__ diagT,
        f4* __restrict__ out, int n4) {
    int i0 = blockIdx.x * 1024 + threadIdx.x;
    int i1 = i0 + 256, i2 = i0 + 512, i3 = i0 + 768;

    if (i3 < n4) {
        f4 x0 = x[i0];
        f4 x1 = x[i1];
        f4 x2 = x[i2];
        f4 x3 = x[i3];
        f4 d0 = diagT[i0 & (ROW4 - 1)];
        f4 d1 = diagT[i1 & (ROW4 - 1)];
        f4 d2 = diagT[i2 & (ROW4 - 1)];
        f4 d3 = diagT[i3 & (ROW4 - 1)];
        out[i0] = x0 * d0;
        out[i1] = x1 * d1;
        out[i2] = x2 * d2;
        out[i3] = x3 * d3;
    } else {
        for (int i = i0; i < n4; i += 256) {
            out[i] = x[i] * diagT[i & (ROW4 - 1)];
        }
    }
}

// ---------------------------------------------------------------------------
// Fallback (ws too small): fused kernel reading R's diagonal directly; the
// touched diagonal lines are L2-resident after the first (b,h) plane.
// ---------------------------------------------------------------------------
__global__ void rope_scale_fused_kernel(const f4* __restrict__ x,
                                        const float* __restrict__ R,
                                        f4* __restrict__ out, int n4) {
    const int stride = gridDim.x * blockDim.x;
    for (int i = blockIdx.x * blockDim.x + threadIdx.x; i < n4; i += stride) {
        int r  = i & (ROW4 - 1);     // float4 index within one (s,d) plane
        int s  = r >> 5;             // DK/4 = 32 float4 per row
        int d0 = (r & 31) * 4;       // first of 4 consecutive d
        f4 xv = x[i];
        f4 dv;
        dv.x = R[(size_t)((d0 + 0) * DK + (d0 + 0)) * SEQ + s];
        dv.y = R[(size_t)((d0 + 1) * DK + (d0 + 1)) * SEQ + s];
        dv.z = R[(size_t)((d0 + 2) * DK + (d0 + 2)) * SEQ + s];
        dv.w = R[(size_t)((d0 + 3) * DK + (d0 + 3)) * SEQ + s];
        out[i] = xv * dv;
    }
}

extern "C" void kernel_launch(void* const* d_in, const int* in_sizes, int n_in,
                              void* d_out, int out_size, void* d_ws, size_t ws_size,
                              hipStream_t stream) {
    const float* x = (const float*)d_in[0];
    // d_in[1] = token_positions — unused by the reference.
    const float* R = (const float*)d_in[2];
    float* out = (float*)d_out;

    const int n  = out_size;        // 8*16*4096*128 = 67,108,864 elements
    const int n4 = n / 4;           // 16,777,216 float4 elements

    const size_t diag_bytes = (size_t)ROW * sizeof(float);   // 2 MiB

    if (ws_size >= diag_bytes) {
        float* diagT = (float*)d_ws;
        extract_diag_kernel<<<(ROW + 255) / 256, 256, 0, stream>>>(R, diagT);
        rope_scale_kernel<<<(n4 + 1023) / 1024, 256, 0, stream>>>(
            (const f4*)x, (const f4*)diagT, (f4*)out, n4);
    } else {
        rope_scale_fused_kernel<<<2048, 256, 0, stream>>>(
            (const f4*)x, R, (f4*)out, n4);
    }
}